// Round 9
// baseline (282.082 us; speedup 1.0000x reference)
//
#include <hip/hip_runtime.h>

#define Bn 8
#define CINn 64
#define COUTn 64
#define Hn 128
#define Wn 128
#define KKn 9

typedef __attribute__((ext_vector_type(8))) short short8v;   // 8 bf16 (4 VGPR)
typedef __attribute__((ext_vector_type(4))) float f32x4;     // MFMA accumulator

__device__ __forceinline__ unsigned short f2bf(float f) {
    unsigned u = __float_as_uint(f);
    unsigned r = (u + 0x7FFFu + ((u >> 16) & 1u)) >> 16;     // RNE
    return (unsigned short)r;
}
__device__ __forceinline__ float bf2f(unsigned short u) {
    return __uint_as_float(((unsigned)u) << 16);
}

// ---------------------------------------------------------------------------
// xt_prep: x f32 NCHW -> xt bf16 NHWC  (xt[b][y][x][c], c contiguous)
// ---------------------------------------------------------------------------
__launch_bounds__(256)
__global__ void xt_prep(const float* __restrict__ x, unsigned short* __restrict__ xt) {
    __shared__ unsigned short tile[128 * 68];        // 17408 B
    const int blk = blockIdx.x;
    const int b = blk >> 7, y = blk & 127;
    const int t = threadIdx.x;
    const float* xb = x + (((long)b * CINn) << 14) + (y << 7);
#pragma unroll
    for (int i = 0; i < 32; ++i) {
        int e = i * 256 + t;                         // c = e>>7, xx = e&127
        int c = e >> 7, xx = e & 127;
        tile[xx * 68 + c] = f2bf(xb[((long)c << 14) + xx]);
    }
    __syncthreads();
    unsigned short* dst = xt + ((long)(b * 128 + y) << 13);
#pragma unroll
    for (int i = 0; i < 4; ++i) {
        int q = i * 256 + t;                         // 16B chunk: xx = q>>3, j = q&7
        int xx = q >> 3, j = q & 7;
        const unsigned long long* src = (const unsigned long long*)&tile[xx * 68 + j * 8];
        unsigned long long v0 = src[0], v1 = src[1];
        unsigned long long* d = (unsigned long long*)&dst[q * 8];
        d[0] = v0; d[1] = v1;
    }
}

// ---------------------------------------------------------------------------
// wdcn_prep: w_dcn (COUT, CIN, 3,3) -> bf16 w2[k][o][c]
// ---------------------------------------------------------------------------
__global__ void wdcn_prep(const float* __restrict__ w_dcn, unsigned short* __restrict__ w2) {
    int i = blockIdx.x * 256 + threadIdx.x;          // 36864 = [k][o][c]
    if (i >= COUTn * CINn * KKn) return;
    int c = i & 63;
    int o = (i >> 6) & 63;
    int k = i >> 12;
    w2[i] = f2bf(w_dcn[(o * CINn + c) * KKn + k]);
}

// ---------------------------------------------------------------------------
// woffprep: w_off (27, 64, 3,3) -> bf16 wofft[tap][ch pad32][c]  (zeros ch>=27)
// ---------------------------------------------------------------------------
__global__ void woffprep(const float* __restrict__ w_off, unsigned short* __restrict__ wofft) {
    int i = blockIdx.x * 256 + threadIdx.x;          // 18432 = [tap][ch][c]
    if (i >= 9 * 32 * 64) return;
    int c   = i & 63;
    int ch  = (i >> 6) & 31;
    int tap = i >> 11;
    wofft[i] = (ch < 27) ? f2bf(w_off[(ch * 64 + c) * 9 + tap]) : (unsigned short)0;
}

// ---------------------------------------------------------------------------
// offconv_direct: off via MFMA, zero LDS.  Block = (b, h, half-row): 2048
// blocks (8/CU).  Wave wv owns 16 pos x both ch-tiles.  B-frags straight from
// xt (NHWC); OOB taps -> zero.  Output offo PIXEL-MAJOR bf16 [b][h][w][32ch].
// ---------------------------------------------------------------------------
__launch_bounds__(256)
__global__ void offconv_direct(const unsigned short* __restrict__ xt,
                               const unsigned short* __restrict__ wofft,
                               const float* __restrict__ b_off,
                               unsigned short* __restrict__ offo) {
    int blk = blockIdx.x;
    blk = (blk & 7) * 256 + (blk >> 3);              // XCD swizzle (2048%8==0): b = orig&7
    const int b = blk >> 8, h = (blk >> 1) & 127, ph = blk & 1;
    const int t = threadIdx.x;
    const int lane = t & 63, wv = t >> 6;
    const int r16 = lane & 15, sub = lane >> 4;
    const int wbase = ph * 64 + wv * 16;
    const unsigned short* xtb = xt + ((long)b << 20);

    f32x4 acc[2];
    acc[0] = (f32x4){0.f, 0.f, 0.f, 0.f};
    acc[1] = (f32x4){0.f, 0.f, 0.f, 0.f};
    const short8v zf = {0, 0, 0, 0, 0, 0, 0, 0};

#pragma unroll
    for (int di = 0; di < 3; ++di) {
        const int y = h + di - 1;
        const bool yok = (y >= 0 && y < Hn);
        const int yc = yok ? y : 0;
#pragma unroll
        for (int dj = 0; dj < 3; ++dj) {
            const int tap = di * 3 + dj;
#pragma unroll
            for (int kk = 0; kk < 2; ++kk) {
                const int cc8 = (kk * 4 + sub) << 3;
                short8v a0 = *(const short8v*)(wofft + ((tap * 32 +      r16) << 6) + cc8);
                short8v a1 = *(const short8v*)(wofft + ((tap * 32 + 16 + r16) << 6) + cc8);
                int w = wbase + r16 + dj - 1;
                bool valid = yok && (w >= 0 && w < Wn);
                int wc = valid ? w : 0;
                short8v v = *(const short8v*)(xtb + (yc << 13) + (wc << 6) + cc8);
                short8v bfr = valid ? v : zf;
                acc[0] = __builtin_amdgcn_mfma_f32_16x16x32_bf16(a0, bfr, acc[0], 0, 0, 0);
                acc[1] = __builtin_amdgcn_mfma_f32_16x16x32_bf16(a1, bfr, acc[1], 0, 0, 0);
            }
        }
    }

    // epilogue: D col=r16 (w), row=sub*4+r (ch); bias add; pixel-major bf16
    unsigned short* po = offo + ((((long)b << 7) + h) << 12) + ((wbase + r16) << 5);
#pragma unroll
    for (int mt = 0; mt < 2; ++mt) {
#pragma unroll
        for (int r = 0; r < 4; ++r) {
            int ch = mt * 16 + sub * 4 + r;
            if (ch < 27)
                po[ch] = f2bf(acc[mt][r] + b_off[ch]);
        }
    }
}

// ---------------------------------------------------------------------------
// dcn_direct: deformable conv, zero LDS.  Block = (b, h, half-row): 2048
// blocks (8/CU).  Wave wv owns 16 pos x ALL 4 cout tiles.  Per-lane offsets
// read from its own 64B pixel record (L1-resident across k).  Corner loads
// 16B from xt (NHWC bf16); A-frags wave-uniform from w2.
// ---------------------------------------------------------------------------
__launch_bounds__(256)
__global__ void dcn_direct(const unsigned short* __restrict__ xt,
                           const unsigned short* __restrict__ offo,
                           const unsigned short* __restrict__ w2,
                           float* __restrict__ out) {
    int blk = blockIdx.x;
    blk = (blk & 7) * 256 + (blk >> 3);              // XCD swizzle: b = orig&7
    const int b = blk >> 8, h = (blk >> 1) & 127, ph = blk & 1;
    const int t = threadIdx.x;
    const int lane = t & 63, wv = t >> 6;
    const int r16 = lane & 15, sub = lane >> 4;
    const int pos = ph * 64 + wv * 16 + r16;
    const unsigned short* xtb = xt + ((long)b << 20);
    const unsigned short* pix = offo + ((((long)b << 7) + h) << 12) + (pos << 5);

    f32x4 acc[4];
#pragma unroll
    for (int ot = 0; ot < 4; ++ot) acc[ot] = (f32x4){0.f, 0.f, 0.f, 0.f};

    for (int k = 0; k < KKn; ++k) {
        const int ky = k / 3 - 1, kx = k % 3 - 1;
        // ---- per-lane bilinear params from own pixel record ----
        unsigned dydx = *(const unsigned*)(pix + 2 * k);
        float dy = bf2f((unsigned short)(dydx & 0xffffu));
        float dx = bf2f((unsigned short)(dydx >> 16));
        float m  = bf2f(pix[18 + k]);
        m = 1.f / (1.f + __expf(-m));
        float py = (float)(h + ky) + dy;
        float px = (float)(pos + kx) + dx;
        float fy = floorf(py), fx = floorf(px);
        int y0 = (int)fy, x0 = (int)fx;
        float wy1 = py - fy, wx1 = px - fx;
        float a0 = (y0 >= 0     && y0 < Hn)     ? (1.f - wy1) * m : 0.f;
        float a1 = (y0 + 1 >= 0 && y0 + 1 < Hn) ? wy1 * m         : 0.f;
        float b0 = (x0 >= 0     && x0 < Wn)     ? (1.f - wx1)     : 0.f;
        float b1 = (x0 + 1 >= 0 && x0 + 1 < Wn) ? wx1             : 0.f;
        float q00 = a0 * b0, q01 = a0 * b1, q10 = a1 * b0, q11 = a1 * b1;
        int y0c = min(max(y0, 0), Hn - 1), y1c = min(max(y0 + 1, 0), Hn - 1);
        int x0c = min(max(x0, 0), Wn - 1), x1c = min(max(x0 + 1, 0), Wn - 1);
        int o00 = (y0c << 13) + (x0c << 6), o01 = (y0c << 13) + (x1c << 6);
        int o10 = (y1c << 13) + (x0c << 6), o11 = (y1c << 13) + (x1c << 6);

#pragma unroll
        for (int kk = 0; kk < 2; ++kk) {
            const int cc8 = (kk * 4 + sub) << 3;
            short8v af[4];
#pragma unroll
            for (int ot = 0; ot < 4; ++ot)
                af[ot] = *(const short8v*)(w2 + (k << 12) + ((ot * 16 + r16) << 6) + cc8);
            short8v c00 = *(const short8v*)(xtb + o00 + cc8);
            short8v c01 = *(const short8v*)(xtb + o01 + cc8);
            short8v c10 = *(const short8v*)(xtb + o10 + cc8);
            short8v c11 = *(const short8v*)(xtb + o11 + cc8);
            const unsigned* u00 = (const unsigned*)&c00;
            const unsigned* u01 = (const unsigned*)&c01;
            const unsigned* u10 = (const unsigned*)&c10;
            const unsigned* u11 = (const unsigned*)&c11;
            short8v bfv;
            unsigned* ub = (unsigned*)&bfv;
#pragma unroll
            for (int jj = 0; jj < 4; ++jj) {
                float f00l = __uint_as_float(u00[jj] << 16), f00h = __uint_as_float(u00[jj] & 0xffff0000u);
                float f01l = __uint_as_float(u01[jj] << 16), f01h = __uint_as_float(u01[jj] & 0xffff0000u);
                float f10l = __uint_as_float(u10[jj] << 16), f10h = __uint_as_float(u10[jj] & 0xffff0000u);
                float f11l = __uint_as_float(u11[jj] << 16), f11h = __uint_as_float(u11[jj] & 0xffff0000u);
                float tl = q00 * f00l + q01 * f01l + q10 * f10l + q11 * f11l;
                float th = q00 * f00h + q01 * f01h + q10 * f10h + q11 * f11h;
                ub[jj] = (unsigned)f2bf(tl) | ((unsigned)f2bf(th) << 16);
            }
#pragma unroll
            for (int ot = 0; ot < 4; ++ot)
                acc[ot] = __builtin_amdgcn_mfma_f32_16x16x32_bf16(af[ot], bfv, acc[ot], 0, 0, 0);
        }
    }

    // epilogue: D col=r16 (pos), row=sub*4+r (cout)
    const long obase = (((long)b * COUTn) << 14) + (h << 7);
#pragma unroll
    for (int ot = 0; ot < 4; ++ot) {
#pragma unroll
        for (int r = 0; r < 4; ++r) {
            int o = ot * 16 + sub * 4 + r;
            out[obase + ((long)o << 14) + pos] = acc[ot][r];
        }
    }
}

// ---------------------------------------------------------------------------
extern "C" void kernel_launch(void* const* d_in, const int* in_sizes, int n_in,
                              void* d_out, int out_size, void* d_ws, size_t ws_size,
                              hipStream_t stream) {
    const float* x     = (const float*)d_in[0];
    const float* w_off = (const float*)d_in[1];
    const float* b_off = (const float*)d_in[2];
    const float* w_dcn = (const float*)d_in[3];
    float* out = (float*)d_out;

    unsigned short* xt    = (unsigned short*)d_ws;                      // 16777216 B
    unsigned short* w2    = (unsigned short*)((char*)d_ws + 16777216);  //    73728 B
    unsigned short* wofft = (unsigned short*)((char*)d_ws + 16850944);  //    36864 B
    unsigned short* offo  = (unsigned short*)((char*)d_ws + 16887808);  //  8388608 B  [b][h][w][32]

    xt_prep<<<Bn * Hn, 256, 0, stream>>>(x, xt);
    wdcn_prep<<<144, 256, 0, stream>>>(w_dcn, w2);
    woffprep<<<72, 256, 0, stream>>>(w_off, wofft);
    offconv_direct<<<2 * Bn * Hn, 256, 0, stream>>>(xt, wofft, b_off, offo);
    dcn_direct<<<2 * Bn * Hn, 256, 0, stream>>>(xt, offo, w2, out);
}